// Round 12
// baseline (207.557 us; speedup 1.0000x reference)
//
#include <hip/hip_runtime.h>
#include <hip/hip_bf16.h>

typedef __attribute__((ext_vector_type(8))) short short8;     // 8 bf16 MFMA operand
typedef __attribute__((ext_vector_type(4))) float f32x4;
typedef __attribute__((ext_vector_type(8))) unsigned short ushort8v;

// B=2, T=2048, D_IN=1024, H=16, D_HEAD=64, D_INNER=1024, M=B*T=4096

__device__ __forceinline__ unsigned short f2bf(float f) {
  union { float f; unsigned int u; } x; x.f = f;
  unsigned int r = x.u + 0x7FFFu + ((x.u >> 16) & 1u);   // RNE
  return (unsigned short)(r >> 16);
}

__device__ __forceinline__ unsigned int pk2bf(float lo, float hi) {
  __hip_bfloat162 b2 = __float22bfloat162_rn(make_float2(lo, hi));
  union { __hip_bfloat162 b; unsigned int u; } c; c.b = b2;
  return c.u;
}

__device__ __forceinline__ void gload_lds16(const void* g, void* l) {
  __builtin_amdgcn_global_load_lds(
      (const __attribute__((address_space(1))) void*)g,
      (__attribute__((address_space(3))) void*)l, 16, 0, 0);
}

// ---------------- fused prep: bias_init + x->bf16 + 4 weight transposes ----------------
// grid: [0,4096) cvt x | [4096,7168) Wq/Wk/Wv transpose | [7168,7232) Wo | [7232,7488) bias

__global__ __launch_bounds__(256) void prep(
    const float* __restrict__ x,
    const float* __restrict__ Wq, const float* __restrict__ Wk, const float* __restrict__ Wv,
    const float* __restrict__ Wo, const float* __restrict__ bo,
    unsigned short* __restrict__ xb,
    unsigned short* __restrict__ wqt, unsigned short* __restrict__ wkt,
    unsigned short* __restrict__ wvt, unsigned short* __restrict__ wot,
    float* __restrict__ out) {
  __shared__ float tile[32][33];
  int b = blockIdx.x;
  if (b < 4096) {                     // x -> bf16, 4 elems/thread
    int i = (b * 256 + threadIdx.x) * 4;
    float4 f = *(const float4*)(x + i);
    ushort4 o;
    o.x = f2bf(f.x); o.y = f2bf(f.y); o.z = f2bf(f.z); o.w = f2bf(f.w);
    *(ushort4*)(xb + i) = o;
  } else if (b < 7168) {              // W^T for Wq/Wk/Wv (1024x1024)
    int idx = b - 4096;
    int z = idx >> 10, rem = idx & 1023;
    const float* src = (z == 0) ? Wq : (z == 1) ? Wk : Wv;
    unsigned short* dst = (z == 0) ? wqt : (z == 1) ? wkt : wvt;
    int kx = (rem & 31) * 32, ny = (rem >> 5) * 32;
    int tx = threadIdx.x & 31, ty = threadIdx.x >> 5;
    #pragma unroll
    for (int r = 0; r < 32; r += 8)
      tile[ty + r][tx] = src[(size_t)(kx + ty + r) * 1024 + ny + tx];
    __syncthreads();
    #pragma unroll
    for (int r = 0; r < 32; r += 8)
      dst[(size_t)(ny + ty + r) * 1024 + kx + tx] = f2bf(tile[tx][ty + r]);
  } else if (b < 7232) {              // Wo^T (1024x64 -> 64x1024)
    int idx = b - 7168;
    int kx = (idx & 31) * 32, ny = (idx >> 5) * 32;
    int tx = threadIdx.x & 31, ty = threadIdx.x >> 5;
    #pragma unroll
    for (int r = 0; r < 32; r += 8)
      tile[ty + r][tx] = Wo[(size_t)(kx + ty + r) * 64 + ny + tx];
    __syncthreads();
    #pragma unroll
    for (int r = 0; r < 32; r += 8)
      wot[(size_t)(ny + ty + r) * 1024 + kx + tx] = f2bf(tile[tx][ty + r]);
  } else {                            // seed out with bias (out is re-poisoned each call)
    int t = (b - 7232) * 256 + threadIdx.x;  // 65536 float4s
    float4 bi = *(const float4*)(bo + (t & 15) * 4);
    *(float4*)(out + (size_t)t * 4) = bi;
  }
}

// ---------------- QKV projection GEMM v5: direct-to-register, NO LDS, NO barriers ----------------
// Both MFMA fragments are row-contiguous 16B/lane == one global_load_dwordx4 each.
// LDS staging only shared rows between 2 of 4 waves; L1/L2 serve that duplication.
// 8 per-lane base pointers, K-loop fully unrolled: all loads use compile-time
// immediate offsets (kt*64B <= 1984 < 4095). Register prefetch depth 1.
// W 6MB + X 8MB stay L2/L3-resident. Grid 768 (24 mt x 32 nt), XCD-bijective swizzle.

__global__ __launch_bounds__(256, 3) void qkv_gemm5(
    const unsigned short* __restrict__ Xb,
    const unsigned short* __restrict__ Wstk,
    unsigned short* __restrict__ Oq, unsigned short* __restrict__ Ok,
    unsigned short* __restrict__ Ovt) {
  constexpr int Kd = 1024;
  int wg = blockIdx.x;                       // 768 = 24 m-tiles x 32 n-tiles
  int swz8 = (wg & 7) * 96 + (wg >> 3);      // bijective XCD swizzle (cpx=96)
  int mt = swz8 >> 5, ntile = swz8 & 31;
  int m0 = mt * 128, n0 = ntile * 128;

  int tid = threadIdx.x, lane = tid & 63, wave = tid >> 6;
  int wm = wave >> 1, wn = wave & 1;         // 2x2 wave grid; per-wave C = 64x64
  int l15 = lane & 15, quad = lane >> 4;

  // 8 per-lane base pointers (k=0 position of each fragment row)
  const unsigned short* pA[4];
  const unsigned short* pB[4];
  #pragma unroll
  for (int i = 0; i < 4; ++i) {
    pA[i] = Wstk + (size_t)(m0 + wm * 64 + i * 16 + l15) * Kd + quad * 8;
    pB[i] = Xb  + (size_t)(n0 + wn * 64 + i * 16 + l15) * Kd + quad * 8;
  }

  f32x4 acc[4][4] = {};
  ushort8v a_cur[4], b_cur[4], a_nxt[4], b_nxt[4];

  #pragma unroll
  for (int i = 0; i < 4; ++i) {
    a_cur[i] = *(const ushort8v*)(pA[i]);
    b_cur[i] = *(const ushort8v*)(pB[i]);
  }

  #pragma unroll
  for (int kt = 0; kt < 32; ++kt) {
    if (kt + 1 < 32) {   // prefetch next K-step fragments (imm offset, in flight over MFMAs)
      #pragma unroll
      for (int i = 0; i < 4; ++i) {
        a_nxt[i] = *(const ushort8v*)(pA[i] + (kt + 1) * 32);
        b_nxt[i] = *(const ushort8v*)(pB[i] + (kt + 1) * 32);
      }
    }
    __builtin_amdgcn_s_setprio(1);
    #pragma unroll
    for (int mi = 0; mi < 4; ++mi) {
      short8 af = (short8)a_cur[mi];
      #pragma unroll
      for (int ni = 0; ni < 4; ++ni)
        acc[mi][ni] = __builtin_amdgcn_mfma_f32_16x16x32_bf16(af, (short8)b_cur[ni], acc[mi][ni], 0, 0, 0);
    }
    __builtin_amdgcn_s_setprio(0);
    #pragma unroll
    for (int i = 0; i < 4; ++i) { a_cur[i] = a_nxt[i]; b_cur[i] = b_nxt[i]; }
  }

  // epilogue: region by m (mt 0-7 q, 8-15 k, 16-23 v); per-lane rows = 4 consecutive d
  int region = mt >> 3;
  if (region < 2) {
    unsigned short* O = (region == 0) ? Oq : Ok;
    float scale = (region == 0) ? 0.0450842200f : 1.0f;  // 1/sqrt(1024)*log2(e) for Q
    #pragma unroll
    for (int mi = 0; mi < 4; ++mi) {
      int dg = (m0 - region * 1024) + wm * 64 + mi * 16 + quad * 4;
      int h = dg >> 6, d0 = dg & 63;
      #pragma unroll
      for (int ni = 0; ni < 4; ++ni) {
        int t = n0 + wn * 64 + ni * 16 + l15;
        int b = t >> 11, tt = t & 2047;
        uint2 pk;
        pk.x = pk2bf(acc[mi][ni][0] * scale, acc[mi][ni][1] * scale);
        pk.y = pk2bf(acc[mi][ni][2] * scale, acc[mi][ni][3] * scale);
        *(uint2*)(O + (((size_t)(b * 16 + h) * 2048 + tt) << 6) + d0) = pk;
      }
    }
  } else {
    #pragma unroll
    for (int mi = 0; mi < 4; ++mi) {
      int dg = (m0 - 2048) + wm * 64 + mi * 16 + quad * 4;
      int h = dg >> 6, d0 = dg & 63;
      #pragma unroll
      for (int ni = 0; ni < 4; ++ni) {
        int t = n0 + wn * 64 + ni * 16 + l15;
        int b = t >> 11, tt = t & 2047;
        #pragma unroll
        for (int r = 0; r < 4; ++r)
          Ovt[(((size_t)(b * 16 + h) * 64 + d0 + r) << 11) + tt] = f2bf(acc[mi][ni][r]);
      }
    }
  }
}

// ---------------- fused causal flash attention v14: shuffle-light softmax ----------------
// Defer-check first on per-lane max (skip both max shuffles when defer); per-lane
// partial denominator reduced once in the epilogue. Common path: 0 shuffles/iter.
// XOR-swz LDS, dbuf write-late, exp2 domain, setprio, fused out-proj epilogue.

__global__ __launch_bounds__(256, 4) void attn14(
    const unsigned short* __restrict__ Qg, const unsigned short* __restrict__ Kg,
    const unsigned short* __restrict__ Vtg, const unsigned short* __restrict__ Wot,
    float* __restrict__ out) {
  constexpr int T = 2048;
  __shared__ __align__(16) unsigned short Ks[2][64 * 64];   // [tok][d], XOR-swz
  __shared__ __align__(16) unsigned short Vs[2][64 * 64];   // [d][tok], XOR-swz
  __shared__ __align__(16) unsigned short Ps[4][16 * 64];   // per-wave, XOR-swz
  int bh = blockIdx.x;
  int by = blockIdx.y;
  int g = by >> 3, w8 = by & 7;
  int qt = (g == 0) ? w8 : (g == 1) ? (15 - w8) : (g == 2) ? (16 + w8) : (31 - w8);
  int tid = threadIdx.x, lane = tid & 63, wave = tid >> 6;
  int l15 = lane & 15, quad = lane >> 4;
  int swz = l15 & 7;
  const unsigned short* Qb = Qg + (size_t)bh * T * 64;
  const unsigned short* Kb = Kg + (size_t)bh * T * 64;
  const unsigned short* Vb = Vtg + (size_t)bh * 64 * T;
  int h = bh & 15, b = bh >> 4;
  int qw = qt * 64 + wave * 16;

  short8 qf[2];
  #pragma unroll
  for (int s = 0; s < 2; ++s)
    qf[s] = *(const short8*)(Qb + (size_t)(qw + l15) * 64 + quad * 8 + 32 * s);

  f32x4 Oacc[4] = {};
  float m_run = -__builtin_inff();
  float l_part = 0.f;                      // per-lane partial denominator

  int srow = tid >> 3, sc8 = tid & 7;
  int sdst = srow * 64 + ((sc8 ^ (srow & 7)) * 8);

  ushort8v kpre[2], vpre[2];
  #pragma unroll
  for (int r = 0; r < 2; ++r) {
    kpre[r] = *(const ushort8v*)(Kb + (size_t)(srow + 32 * r) * 64 + sc8 * 8);
    vpre[r] = *(const ushort8v*)(Vb + (size_t)(srow + 32 * r) * T + sc8 * 8);
  }
  *(ushort8v*)&Ks[0][sdst] = kpre[0];
  *(ushort8v*)&Ks[0][sdst + 2048] = kpre[1];
  *(ushort8v*)&Vs[0][sdst] = vpre[0];
  *(ushort8v*)&Vs[0][sdst + 2048] = vpre[1];
  __syncthreads();

  for (int kt = 0; kt <= qt; ++kt) {
    const unsigned short* Kl = Ks[kt & 1];
    const unsigned short* Vl = Vs[kt & 1];
    unsigned short* Kn = Ks[(kt & 1) ^ 1];
    unsigned short* Vn = Vs[(kt & 1) ^ 1];

    if (kt < qt) {
      #pragma unroll
      for (int r = 0; r < 2; ++r) {
        kpre[r] = *(const ushort8v*)(Kb + (size_t)((kt + 1) * 64 + srow + 32 * r) * 64 + sc8 * 8);
        vpre[r] = *(const ushort8v*)(Vb + (size_t)(srow + 32 * r) * T + (kt + 1) * 64 + sc8 * 8);
      }
    }

    f32x4 S[4] = {};
    __builtin_amdgcn_s_setprio(1);
    #pragma unroll
    for (int s = 0; s < 2; ++s)
      #pragma unroll
      for (int mi = 0; mi < 4; ++mi) {
        short8 kf = *(const short8*)&Kl[(mi * 16 + l15) * 64 + ((quad + 4 * s) ^ swz) * 8];
        S[mi] = __builtin_amdgcn_mfma_f32_16x16x32_bf16(kf, qf[s], S[mi], 0, 0, 0);
      }
    __builtin_amdgcn_s_setprio(0);

    if (kt == qt) {  // diagonal tile: causal mask
      int ql = wave * 16 + l15;
      #pragma unroll
      for (int mi = 0; mi < 4; ++mi) {
        int tokl = mi * 16 + quad * 4;
        #pragma unroll
        for (int r = 0; r < 4; ++r)
          if (tokl + r > ql) S[mi][r] = -__builtin_inff();
      }
    }

    // per-lane max (no shuffles yet)
    float t0 = fmaxf(fmaxf(S[0][0], S[0][1]), fmaxf(S[0][2], S[0][3]));
    float t1 = fmaxf(fmaxf(S[1][0], S[1][1]), fmaxf(S[1][2], S[1][3]));
    float t2 = fmaxf(fmaxf(S[2][0], S[2][1]), fmaxf(S[2][2], S[2][3]));
    float t3 = fmaxf(fmaxf(S[3][0], S[3][1]), fmaxf(S[3][2], S[3][3]));
    float vloc = fmaxf(fmaxf(t0, t1), fmaxf(t2, t3));

    // defer-first: all-lanes check on LOCAL max == check on reduced max.
    float mnew = m_run;
    bool defer = __all(vloc - m_run <= 8.f) != 0;
    if (!defer) {
      float vmax = fmaxf(vloc, __shfl_xor(vloc, 16));
      vmax = fmaxf(vmax, __shfl_xor(vmax, 32));
      mnew = fmaxf(m_run, vmax);
      float alpha = __builtin_amdgcn_exp2f(m_run - mnew);
      m_run = mnew;
      l_part *= alpha;
      #pragma unroll
      for (int jd = 0; jd < 4; ++jd)
        #pragma unroll
        for (int r = 0; r < 4; ++r)
          Oacc[jd][r] *= alpha;
    }

    float rs = 0.f;
    #pragma unroll
    for (int mi = 0; mi < 4; ++mi) {
      float p0 = __builtin_amdgcn_exp2f(S[mi][0] - mnew);
      float p1 = __builtin_amdgcn_exp2f(S[mi][1] - mnew);
      float p2 = __builtin_amdgcn_exp2f(S[mi][2] - mnew);
      float p3 = __builtin_amdgcn_exp2f(S[mi][3] - mnew);
      rs += (p0 + p1) + (p2 + p3);
      uint2 pk;
      pk.x = pk2bf(p0, p1);
      pk.y = pk2bf(p2, p3);
      int gg = (2 * mi + (quad >> 1)) ^ swz;
      *(uint2*)&Ps[wave][l15 * 64 + gg * 8 + (quad & 1) * 4] = pk;
    }
    l_part += rs;                       // per-lane partial; reduced once at end

    if (kt < qt) {
      *(ushort8v*)&Kn[sdst] = kpre[0];
      *(ushort8v*)&Kn[sdst + 2048] = kpre[1];
      *(ushort8v*)&Vn[sdst] = vpre[0];
      *(ushort8v*)&Vn[sdst + 2048] = vpre[1];
    }

    __builtin_amdgcn_s_setprio(1);
    #pragma unroll
    for (int s = 0; s < 2; ++s) {
      short8 pf = *(const short8*)&Ps[wave][l15 * 64 + ((quad + 4 * s) ^ swz) * 8];
      #pragma unroll
      for (int jd = 0; jd < 4; ++jd) {
        short8 vfr = *(const short8*)&Vl[(jd * 16 + l15) * 64 + ((quad + 4 * s) ^ swz) * 8];
        Oacc[jd] = __builtin_amdgcn_mfma_f32_16x16x32_bf16(vfr, pf, Oacc[jd], 0, 0, 0);
      }
    }
    __builtin_amdgcn_s_setprio(0);
    if (kt < qt) __syncthreads();
  }

  // final denominator reduce (2 shuffles total, was 2/iter)
  float l_run = l_part + __shfl_xor(l_part, 16);
  l_run += __shfl_xor(l_run, 32);

  // ---- fused out-projection epilogue (no barriers: each wave uses only its own Ps slot) ----
  {
    float linv = 1.f / l_run;
    unsigned short* Yl = &Ps[wave][0];
    #pragma unroll
    for (int jd = 0; jd < 4; ++jd) {
      uint2 pk;
      pk.x = pk2bf(Oacc[jd][0] * linv, Oacc[jd][1] * linv);
      pk.y = pk2bf(Oacc[jd][2] * linv, Oacc[jd][3] * linv);
      int gg = (jd * 2 + (quad >> 1)) ^ swz;
      *(uint2*)&Yl[l15 * 64 + gg * 8 + (quad & 1) * 4] = pk;
    }
    short8 wof[4][2];
    #pragma unroll
    for (int nt = 0; nt < 4; ++nt)
      #pragma unroll
      for (int s = 0; s < 2; ++s)
        wof[nt][s] = *(const short8*)(Wot + (size_t)(nt * 16 + l15) * 1024 + h * 64 + quad * 8 + 32 * s);
    f32x4 acc2[4] = {};
    #pragma unroll
    for (int s = 0; s < 2; ++s) {
      short8 ya = *(const short8*)&Yl[l15 * 64 + (((quad + 4 * s) ^ swz) * 8)];
      #pragma unroll
      for (int nt = 0; nt < 4; ++nt)
        acc2[nt] = __builtin_amdgcn_mfma_f32_16x16x32_bf16(ya, wof[nt][s], acc2[nt], 0, 0, 0);
    }
    int q0 = b * 2048 + qt * 64 + wave * 16 + quad * 4;
    #pragma unroll
    for (int nt = 0; nt < 4; ++nt)
      #pragma unroll
      for (int r = 0; r < 4; ++r)
        atomicAdd(&out[(size_t)(q0 + r) * 64 + nt * 16 + l15], acc2[nt][r]);
  }
}

// ---------------- launcher (3 kernels total) ----------------

extern "C" void kernel_launch(void* const* d_in, const int* in_sizes, int n_in,
                              void* d_out, int out_size, void* d_ws, size_t ws_size,
                              hipStream_t stream) {
  const float* x  = (const float*)d_in[0];
  const float* Wq = (const float*)d_in[1];
  const float* Wk = (const float*)d_in[2];
  const float* Wv = (const float*)d_in[3];
  const float* Wo = (const float*)d_in[4];
  const float* bo = (const float*)d_in[5];
  float* out = (float*)d_out;
  char* ws = (char*)d_ws;

  unsigned short* xb  = (unsigned short*)(ws);                       // 8 MB  [4096][1024]
  unsigned short* wqt = (unsigned short*)(ws + (8ull << 20));        // 2 MB Wq^T (head of contiguous [3072][1024] W-stack)
  unsigned short* wkt = (unsigned short*)(ws + (10ull << 20));       // 2 MB Wk^T (stack middle)
  unsigned short* wvt = (unsigned short*)(ws + (12ull << 20));       // 2 MB Wv^T (stack tail)
  unsigned short* wot = (unsigned short*)(ws + (14ull << 20));       // 128 KB Wo^T
  unsigned short* q   = (unsigned short*)(ws + (15ull << 20));       // 8 MB  [b][h][t][d]
  unsigned short* k   = (unsigned short*)(ws + (23ull << 20));       // 8 MB  [b][h][t][d]
  unsigned short* vt  = (unsigned short*)(ws + (31ull << 20));       // 8 MB  [b][h][d][t]

  prep<<<7488, 256, 0, stream>>>(x, Wq, Wk, Wv, Wo, bo, xb, wqt, wkt, wvt, wot, out);
  qkv_gemm5<<<768, 256, 0, stream>>>(xb, wqt, q, k, vt);
  attn14<<<dim3(32, 32), 256, 0, stream>>>(q, k, vt, wot, out);
}

// Round 13
// 152.202 us; speedup vs baseline: 1.3637x; 1.3637x over previous
//
#include <hip/hip_runtime.h>
#include <hip/hip_bf16.h>

typedef __attribute__((ext_vector_type(8))) short short8;     // 8 bf16 MFMA operand
typedef __attribute__((ext_vector_type(4))) float f32x4;
typedef __attribute__((ext_vector_type(8))) unsigned short ushort8v;

// B=2, T=2048, D_IN=1024, H=16, D_HEAD=64, D_INNER=1024, M=B*T=4096

__device__ __forceinline__ unsigned short f2bf(float f) {
  union { float f; unsigned int u; } x; x.f = f;
  unsigned int r = x.u + 0x7FFFu + ((x.u >> 16) & 1u);   // RNE
  return (unsigned short)(r >> 16);
}

__device__ __forceinline__ unsigned int pk2bf(float lo, float hi) {
  __hip_bfloat162 b2 = __float22bfloat162_rn(make_float2(lo, hi));
  union { __hip_bfloat162 b; unsigned int u; } c; c.b = b2;
  return c.u;
}

__device__ __forceinline__ void gload_lds16(const void* g, void* l) {
  __builtin_amdgcn_global_load_lds(
      (const __attribute__((address_space(1))) void*)g,
      (__attribute__((address_space(3))) void*)l, 16, 0, 0);
}

// ---------------- fused prep: bias_init + x->bf16 + 4 weight transposes ----------------
// grid: [0,4096) cvt x | [4096,7168) Wq/Wk/Wv transpose | [7168,7232) Wo | [7232,7488) bias

__global__ __launch_bounds__(256) void prep(
    const float* __restrict__ x,
    const float* __restrict__ Wq, const float* __restrict__ Wk, const float* __restrict__ Wv,
    const float* __restrict__ Wo, const float* __restrict__ bo,
    unsigned short* __restrict__ xb,
    unsigned short* __restrict__ wqt, unsigned short* __restrict__ wkt,
    unsigned short* __restrict__ wvt, unsigned short* __restrict__ wot,
    float* __restrict__ out) {
  __shared__ float tile[32][33];
  int b = blockIdx.x;
  if (b < 4096) {                     // x -> bf16, 4 elems/thread
    int i = (b * 256 + threadIdx.x) * 4;
    float4 f = *(const float4*)(x + i);
    ushort4 o;
    o.x = f2bf(f.x); o.y = f2bf(f.y); o.z = f2bf(f.z); o.w = f2bf(f.w);
    *(ushort4*)(xb + i) = o;
  } else if (b < 7168) {              // W^T for Wq/Wk/Wv (1024x1024)
    int idx = b - 4096;
    int z = idx >> 10, rem = idx & 1023;
    const float* src = (z == 0) ? Wq : (z == 1) ? Wk : Wv;
    unsigned short* dst = (z == 0) ? wqt : (z == 1) ? wkt : wvt;
    int kx = (rem & 31) * 32, ny = (rem >> 5) * 32;
    int tx = threadIdx.x & 31, ty = threadIdx.x >> 5;
    #pragma unroll
    for (int r = 0; r < 32; r += 8)
      tile[ty + r][tx] = src[(size_t)(kx + ty + r) * 1024 + ny + tx];
    __syncthreads();
    #pragma unroll
    for (int r = 0; r < 32; r += 8)
      dst[(size_t)(ny + ty + r) * 1024 + kx + tx] = f2bf(tile[tx][ty + r]);
  } else if (b < 7232) {              // Wo^T (1024x64 -> 64x1024)
    int idx = b - 7168;
    int kx = (idx & 31) * 32, ny = (idx >> 5) * 32;
    int tx = threadIdx.x & 31, ty = threadIdx.x >> 5;
    #pragma unroll
    for (int r = 0; r < 32; r += 8)
      tile[ty + r][tx] = Wo[(size_t)(kx + ty + r) * 64 + ny + tx];
    __syncthreads();
    #pragma unroll
    for (int r = 0; r < 32; r += 8)
      wot[(size_t)(ny + ty + r) * 1024 + kx + tx] = f2bf(tile[tx][ty + r]);
  } else {                            // seed out with bias (out is re-poisoned each call)
    int t = (b - 7232) * 256 + threadIdx.x;  // 65536 float4s
    float4 bi = *(const float4*)(bo + (t & 15) * 4);
    *(float4*)(out + (size_t)t * 4) = bi;
  }
}

// ---------------- QKV projection GEMM v3 (measured best: 149.4us config) ----------------
// 128^2 tile, BK=32, 2-slot counted pipeline, 4 blocks/CU, grid 768.
// v4 depth-2 (3 blocks/CU): neutral. v5 no-LDS: FETCH 101MB -> HBM-bound, 96us.
// LDS staging is the traffic compressor, not just latency hiding. Keep v3.

__global__ __launch_bounds__(256, 4) void qkv_gemm3(
    const unsigned short* __restrict__ Xb,
    const unsigned short* __restrict__ Wstk,
    unsigned short* __restrict__ Oq, unsigned short* __restrict__ Ok,
    unsigned short* __restrict__ Ovt) {
  constexpr int Kd = 1024, BK = 32, NT = Kd / BK;  // 32 k-tiles
  __shared__ __align__(16) unsigned short As[2][128 * 32];
  __shared__ __align__(16) unsigned short Bs[2][128 * 32];

  int wg = blockIdx.x;                       // 768 = 24 m-tiles x 32 n-tiles
  int swz8 = (wg & 7) * 96 + (wg >> 3);      // bijective XCD swizzle (cpx=96)
  int mt = swz8 >> 5, ntile = swz8 & 31;     // ntile fastest: same-XCD neighbors share A
  int m0 = mt * 128, n0 = ntile * 128;

  int tid = threadIdx.x, lane = tid & 63, wave = tid >> 6;
  int wm = wave >> 1, wn = wave & 1;         // 2x2 wave grid; per-wave C = 64x64
  int l15 = lane & 15, quad = lane >> 4;

  // staging: i = tid, tid+256 -> row = i>>2 (0..127), granule g = i&3.
  // global granule = g ^ ((row>>1)&3); LDS dest linear i*16B.
  int sr0 = tid >> 2, sg0 = tid & 3;
  int sr1 = (tid + 256) >> 2, sg1 = (tid + 256) & 3;
  int ga0 = (sg0 ^ ((sr0 >> 1) & 3)) * 8, ga1 = (sg1 ^ ((sr1 >> 1) & 3)) * 8;

  f32x4 acc[4][4] = {};

  // prologue: stage tile 0 into slot 0
  gload_lds16(Wstk + (size_t)(m0 + sr0) * Kd + ga0, &As[0][tid * 8]);
  gload_lds16(Wstk + (size_t)(m0 + sr1) * Kd + ga1, &As[0][(tid + 256) * 8]);
  gload_lds16(Xb + (size_t)(n0 + sr0) * Kd + ga0, &Bs[0][tid * 8]);
  gload_lds16(Xb + (size_t)(n0 + sr1) * Kd + ga1, &Bs[0][(tid + 256) * 8]);

  for (int i = 0; i < NT; ++i) {
    int cur = i & 1;
    asm volatile("s_waitcnt vmcnt(0)" ::: "memory");   // tile i landed (mine)
    __builtin_amdgcn_s_barrier();                      // all waves' tile i visible
    __builtin_amdgcn_sched_barrier(0);

    if (i + 1 < NT) {                                  // stage tile i+1 -> other slot
      int k0 = (i + 1) * BK;
      gload_lds16(Wstk + (size_t)(m0 + sr0) * Kd + k0 + ga0, &As[cur ^ 1][tid * 8]);
      gload_lds16(Wstk + (size_t)(m0 + sr1) * Kd + k0 + ga1, &As[cur ^ 1][(tid + 256) * 8]);
      gload_lds16(Xb + (size_t)(n0 + sr0) * Kd + k0 + ga0, &Bs[cur ^ 1][tid * 8]);
      gload_lds16(Xb + (size_t)(n0 + sr1) * Kd + k0 + ga1, &Bs[cur ^ 1][(tid + 256) * 8]);
    }

    // compute tile i from slot cur: 8 ds_read_b128 + 16 MFMA
    {
      const unsigned short* Ab = As[cur];
      const unsigned short* Bb = Bs[cur];
      short8 bfr[4];
      #pragma unroll
      for (int ni = 0; ni < 4; ++ni) {
        int row = wn * 64 + ni * 16 + l15;
        bfr[ni] = *(const short8*)&Bb[row * 32 + ((quad ^ ((row >> 1) & 3)) * 8)];
      }
      __builtin_amdgcn_s_setprio(1);
      #pragma unroll
      for (int mi = 0; mi < 4; ++mi) {
        int row = wm * 64 + mi * 16 + l15;
        short8 af = *(const short8*)&Ab[row * 32 + ((quad ^ ((row >> 1) & 3)) * 8)];
        #pragma unroll
        for (int ni = 0; ni < 4; ++ni)
          acc[mi][ni] = __builtin_amdgcn_mfma_f32_16x16x32_bf16(af, bfr[ni], acc[mi][ni], 0, 0, 0);
      }
      __builtin_amdgcn_s_setprio(0);
    }
  }

  // epilogue: region by m (mt 0-7 q, 8-15 k, 16-23 v); per-lane rows = 4 consecutive d
  int region = mt >> 3;
  if (region < 2) {
    unsigned short* O = (region == 0) ? Oq : Ok;
    float scale = (region == 0) ? 0.0450842200f : 1.0f;  // 1/sqrt(1024)*log2(e) for Q
    #pragma unroll
    for (int mi = 0; mi < 4; ++mi) {
      int dg = (m0 - region * 1024) + wm * 64 + mi * 16 + quad * 4;
      int h = dg >> 6, d0 = dg & 63;
      #pragma unroll
      for (int ni = 0; ni < 4; ++ni) {
        int t = n0 + wn * 64 + ni * 16 + l15;
        int b = t >> 11, tt = t & 2047;
        uint2 pk;
        pk.x = pk2bf(acc[mi][ni][0] * scale, acc[mi][ni][1] * scale);
        pk.y = pk2bf(acc[mi][ni][2] * scale, acc[mi][ni][3] * scale);
        *(uint2*)(O + (((size_t)(b * 16 + h) * 2048 + tt) << 6) + d0) = pk;
      }
    }
  } else {
    #pragma unroll
    for (int mi = 0; mi < 4; ++mi) {
      int dg = (m0 - 2048) + wm * 64 + mi * 16 + quad * 4;
      int h = dg >> 6, d0 = dg & 63;
      #pragma unroll
      for (int ni = 0; ni < 4; ++ni) {
        int t = n0 + wn * 64 + ni * 16 + l15;
        int b = t >> 11, tt = t & 2047;
        #pragma unroll
        for (int r = 0; r < 4; ++r)
          Ovt[(((size_t)(b * 16 + h) * 64 + d0 + r) << 11) + tt] = f2bf(acc[mi][ni][r]);
      }
    }
  }
}

// ---------------- fused causal flash attention v14: shuffle-light softmax ----------------
// Defer-check first on per-lane max (skip both max shuffles when defer); per-lane
// partial denominator reduced once in the epilogue. Common path: 0 shuffles/iter.
// XOR-swz LDS, dbuf write-late, exp2 domain, setprio, fused out-proj epilogue.

__global__ __launch_bounds__(256, 4) void attn14(
    const unsigned short* __restrict__ Qg, const unsigned short* __restrict__ Kg,
    const unsigned short* __restrict__ Vtg, const unsigned short* __restrict__ Wot,
    float* __restrict__ out) {
  constexpr int T = 2048;
  __shared__ __align__(16) unsigned short Ks[2][64 * 64];   // [tok][d], XOR-swz
  __shared__ __align__(16) unsigned short Vs[2][64 * 64];   // [d][tok], XOR-swz
  __shared__ __align__(16) unsigned short Ps[4][16 * 64];   // per-wave, XOR-swz
  int bh = blockIdx.x;
  int by = blockIdx.y;
  int g = by >> 3, w8 = by & 7;
  int qt = (g == 0) ? w8 : (g == 1) ? (15 - w8) : (g == 2) ? (16 + w8) : (31 - w8);
  int tid = threadIdx.x, lane = tid & 63, wave = tid >> 6;
  int l15 = lane & 15, quad = lane >> 4;
  int swz = l15 & 7;
  const unsigned short* Qb = Qg + (size_t)bh * T * 64;
  const unsigned short* Kb = Kg + (size_t)bh * T * 64;
  const unsigned short* Vb = Vtg + (size_t)bh * 64 * T;
  int h = bh & 15, b = bh >> 4;
  int qw = qt * 64 + wave * 16;

  short8 qf[2];
  #pragma unroll
  for (int s = 0; s < 2; ++s)
    qf[s] = *(const short8*)(Qb + (size_t)(qw + l15) * 64 + quad * 8 + 32 * s);

  f32x4 Oacc[4] = {};
  float m_run = -__builtin_inff();
  float l_part = 0.f;                      // per-lane partial denominator

  int srow = tid >> 3, sc8 = tid & 7;
  int sdst = srow * 64 + ((sc8 ^ (srow & 7)) * 8);

  ushort8v kpre[2], vpre[2];
  #pragma unroll
  for (int r = 0; r < 2; ++r) {
    kpre[r] = *(const ushort8v*)(Kb + (size_t)(srow + 32 * r) * 64 + sc8 * 8);
    vpre[r] = *(const ushort8v*)(Vb + (size_t)(srow + 32 * r) * T + sc8 * 8);
  }
  *(ushort8v*)&Ks[0][sdst] = kpre[0];
  *(ushort8v*)&Ks[0][sdst + 2048] = kpre[1];
  *(ushort8v*)&Vs[0][sdst] = vpre[0];
  *(ushort8v*)&Vs[0][sdst + 2048] = vpre[1];
  __syncthreads();

  for (int kt = 0; kt <= qt; ++kt) {
    const unsigned short* Kl = Ks[kt & 1];
    const unsigned short* Vl = Vs[kt & 1];
    unsigned short* Kn = Ks[(kt & 1) ^ 1];
    unsigned short* Vn = Vs[(kt & 1) ^ 1];

    if (kt < qt) {
      #pragma unroll
      for (int r = 0; r < 2; ++r) {
        kpre[r] = *(const ushort8v*)(Kb + (size_t)((kt + 1) * 64 + srow + 32 * r) * 64 + sc8 * 8);
        vpre[r] = *(const ushort8v*)(Vb + (size_t)(srow + 32 * r) * T + (kt + 1) * 64 + sc8 * 8);
      }
    }

    f32x4 S[4] = {};
    __builtin_amdgcn_s_setprio(1);
    #pragma unroll
    for (int s = 0; s < 2; ++s)
      #pragma unroll
      for (int mi = 0; mi < 4; ++mi) {
        short8 kf = *(const short8*)&Kl[(mi * 16 + l15) * 64 + ((quad + 4 * s) ^ swz) * 8];
        S[mi] = __builtin_amdgcn_mfma_f32_16x16x32_bf16(kf, qf[s], S[mi], 0, 0, 0);
      }
    __builtin_amdgcn_s_setprio(0);

    if (kt == qt) {  // diagonal tile: causal mask
      int ql = wave * 16 + l15;
      #pragma unroll
      for (int mi = 0; mi < 4; ++mi) {
        int tokl = mi * 16 + quad * 4;
        #pragma unroll
        for (int r = 0; r < 4; ++r)
          if (tokl + r > ql) S[mi][r] = -__builtin_inff();
      }
    }

    // per-lane max (no shuffles yet)
    float t0 = fmaxf(fmaxf(S[0][0], S[0][1]), fmaxf(S[0][2], S[0][3]));
    float t1 = fmaxf(fmaxf(S[1][0], S[1][1]), fmaxf(S[1][2], S[1][3]));
    float t2 = fmaxf(fmaxf(S[2][0], S[2][1]), fmaxf(S[2][2], S[2][3]));
    float t3 = fmaxf(fmaxf(S[3][0], S[3][1]), fmaxf(S[3][2], S[3][3]));
    float vloc = fmaxf(fmaxf(t0, t1), fmaxf(t2, t3));

    // defer-first: all-lanes check on LOCAL max == check on reduced max.
    float mnew = m_run;
    bool defer = __all(vloc - m_run <= 8.f) != 0;
    if (!defer) {
      float vmax = fmaxf(vloc, __shfl_xor(vloc, 16));
      vmax = fmaxf(vmax, __shfl_xor(vmax, 32));
      mnew = fmaxf(m_run, vmax);
      float alpha = __builtin_amdgcn_exp2f(m_run - mnew);
      m_run = mnew;
      l_part *= alpha;
      #pragma unroll
      for (int jd = 0; jd < 4; ++jd)
        #pragma unroll
        for (int r = 0; r < 4; ++r)
          Oacc[jd][r] *= alpha;
    }

    float rs = 0.f;
    #pragma unroll
    for (int mi = 0; mi < 4; ++mi) {
      float p0 = __builtin_amdgcn_exp2f(S[mi][0] - mnew);
      float p1 = __builtin_amdgcn_exp2f(S[mi][1] - mnew);
      float p2 = __builtin_amdgcn_exp2f(S[mi][2] - mnew);
      float p3 = __builtin_amdgcn_exp2f(S[mi][3] - mnew);
      rs += (p0 + p1) + (p2 + p3);
      uint2 pk;
      pk.x = pk2bf(p0, p1);
      pk.y = pk2bf(p2, p3);
      int gg = (2 * mi + (quad >> 1)) ^ swz;
      *(uint2*)&Ps[wave][l15 * 64 + gg * 8 + (quad & 1) * 4] = pk;
    }
    l_part += rs;                       // per-lane partial; reduced once at end

    if (kt < qt) {
      *(ushort8v*)&Kn[sdst] = kpre[0];
      *(ushort8v*)&Kn[sdst + 2048] = kpre[1];
      *(ushort8v*)&Vn[sdst] = vpre[0];
      *(ushort8v*)&Vn[sdst + 2048] = vpre[1];
    }

    __builtin_amdgcn_s_setprio(1);
    #pragma unroll
    for (int s = 0; s < 2; ++s) {
      short8 pf = *(const short8*)&Ps[wave][l15 * 64 + ((quad + 4 * s) ^ swz) * 8];
      #pragma unroll
      for (int jd = 0; jd < 4; ++jd) {
        short8 vfr = *(const short8*)&Vl[(jd * 16 + l15) * 64 + ((quad + 4 * s) ^ swz) * 8];
        Oacc[jd] = __builtin_amdgcn_mfma_f32_16x16x32_bf16(vfr, pf, Oacc[jd], 0, 0, 0);
      }
    }
    __builtin_amdgcn_s_setprio(0);
    if (kt < qt) __syncthreads();
  }

  // final denominator reduce (2 shuffles total, was 2/iter)
  float l_run = l_part + __shfl_xor(l_part, 16);
  l_run += __shfl_xor(l_run, 32);

  // ---- fused out-projection epilogue (no barriers: each wave uses only its own Ps slot) ----
  {
    float linv = 1.f / l_run;
    unsigned short* Yl = &Ps[wave][0];
    #pragma unroll
    for (int jd = 0; jd < 4; ++jd) {
      uint2 pk;
      pk.x = pk2bf(Oacc[jd][0] * linv, Oacc[jd][1] * linv);
      pk.y = pk2bf(Oacc[jd][2] * linv, Oacc[jd][3] * linv);
      int gg = (jd * 2 + (quad >> 1)) ^ swz;
      *(uint2*)&Yl[l15 * 64 + gg * 8 + (quad & 1) * 4] = pk;
    }
    short8 wof[4][2];
    #pragma unroll
    for (int nt = 0; nt < 4; ++nt)
      #pragma unroll
      for (int s = 0; s < 2; ++s)
        wof[nt][s] = *(const short8*)(Wot + (size_t)(nt * 16 + l15) * 1024 + h * 64 + quad * 8 + 32 * s);
    f32x4 acc2[4] = {};
    #pragma unroll
    for (int s = 0; s < 2; ++s) {
      short8 ya = *(const short8*)&Yl[l15 * 64 + (((quad + 4 * s) ^ swz) * 8)];
      #pragma unroll
      for (int nt = 0; nt < 4; ++nt)
        acc2[nt] = __builtin_amdgcn_mfma_f32_16x16x32_bf16(ya, wof[nt][s], acc2[nt], 0, 0, 0);
    }
    int q0 = b * 2048 + qt * 64 + wave * 16 + quad * 4;
    #pragma unroll
    for (int nt = 0; nt < 4; ++nt)
      #pragma unroll
      for (int r = 0; r < 4; ++r)
        atomicAdd(&out[(size_t)(q0 + r) * 64 + nt * 16 + l15], acc2[nt][r]);
  }
}

// ---------------- launcher (3 kernels total) ----------------

extern "C" void kernel_launch(void* const* d_in, const int* in_sizes, int n_in,
                              void* d_out, int out_size, void* d_ws, size_t ws_size,
                              hipStream_t stream) {
  const float* x  = (const float*)d_in[0];
  const float* Wq = (const float*)d_in[1];
  const float* Wk = (const float*)d_in[2];
  const float* Wv = (const float*)d_in[3];
  const float* Wo = (const float*)d_in[4];
  const float* bo = (const float*)d_in[5];
  float* out = (float*)d_out;
  char* ws = (char*)d_ws;

  unsigned short* xb  = (unsigned short*)(ws);                       // 8 MB  [4096][1024]
  unsigned short* wqt = (unsigned short*)(ws + (8ull << 20));        // 2 MB Wq^T (head of contiguous [3072][1024] W-stack)
  unsigned short* wkt = (unsigned short*)(ws + (10ull << 20));       // 2 MB Wk^T (stack middle)
  unsigned short* wvt = (unsigned short*)(ws + (12ull << 20));       // 2 MB Wv^T (stack tail)
  unsigned short* wot = (unsigned short*)(ws + (14ull << 20));       // 128 KB Wo^T
  unsigned short* q   = (unsigned short*)(ws + (15ull << 20));       // 8 MB  [b][h][t][d]
  unsigned short* k   = (unsigned short*)(ws + (23ull << 20));       // 8 MB  [b][h][t][d]
  unsigned short* vt  = (unsigned short*)(ws + (31ull << 20));       // 8 MB  [b][h][d][t]

  prep<<<7488, 256, 0, stream>>>(x, Wq, Wk, Wv, Wo, bo, xb, wqt, wkt, wvt, wot, out);
  qkv_gemm3<<<768, 256, 0, stream>>>(xb, wqt, q, k, vt);
  attn14<<<dim3(32, 32), 256, 0, stream>>>(q, k, vt, wot, out);
}

// Round 14
// 151.093 us; speedup vs baseline: 1.3737x; 1.0073x over previous
//
#include <hip/hip_runtime.h>
#include <hip/hip_bf16.h>

typedef __attribute__((ext_vector_type(8))) short short8;     // 8 bf16 MFMA operand
typedef __attribute__((ext_vector_type(4))) float f32x4;
typedef __attribute__((ext_vector_type(8))) unsigned short ushort8v;

// B=2, T=2048, D_IN=1024, H=16, D_HEAD=64, D_INNER=1024, M=B*T=4096

__device__ __forceinline__ unsigned short f2bf(float f) {
  union { float f; unsigned int u; } x; x.f = f;
  unsigned int r = x.u + 0x7FFFu + ((x.u >> 16) & 1u);   // RNE
  return (unsigned short)(r >> 16);
}

__device__ __forceinline__ unsigned int pk2bf(float lo, float hi) {
  __hip_bfloat162 b2 = __float22bfloat162_rn(make_float2(lo, hi));
  union { __hip_bfloat162 b; unsigned int u; } c; c.b = b2;
  return c.u;
}

__device__ __forceinline__ void gload_lds16(const void* g, void* l) {
  __builtin_amdgcn_global_load_lds(
      (const __attribute__((address_space(1))) void*)g,
      (__attribute__((address_space(3))) void*)l, 16, 0, 0);
}

// ---------------- fused prep: bias_init + x->bf16 + 4 weight transposes ----------------
// virtual blocks: [0,4096) cvt x | [4096,7168) Wq/Wk/Wv transpose | [7168,7232) Wo |
// [7232,7488) bias. Grid 1024 + stride loop (was 7488 tiny blocks -> dispatch ramp).

__global__ __launch_bounds__(256) void prep(
    const float* __restrict__ x,
    const float* __restrict__ Wq, const float* __restrict__ Wk, const float* __restrict__ Wv,
    const float* __restrict__ Wo, const float* __restrict__ bo,
    unsigned short* __restrict__ xb,
    unsigned short* __restrict__ wqt, unsigned short* __restrict__ wkt,
    unsigned short* __restrict__ wvt, unsigned short* __restrict__ wot,
    float* __restrict__ out) {
  __shared__ float tile[32][33];
  for (int b = blockIdx.x; b < 7488; b += 1024) {
    if (b < 4096) {                     // x -> bf16, 4 elems/thread
      int i = (b * 256 + threadIdx.x) * 4;
      float4 f = *(const float4*)(x + i);
      ushort4 o;
      o.x = f2bf(f.x); o.y = f2bf(f.y); o.z = f2bf(f.z); o.w = f2bf(f.w);
      *(ushort4*)(xb + i) = o;
    } else if (b < 7168) {              // W^T for Wq/Wk/Wv (1024x1024)
      int idx = b - 4096;
      int z = idx >> 10, rem = idx & 1023;
      const float* src = (z == 0) ? Wq : (z == 1) ? Wk : Wv;
      unsigned short* dst = (z == 0) ? wqt : (z == 1) ? wkt : wvt;
      int kx = (rem & 31) * 32, ny = (rem >> 5) * 32;
      int tx = threadIdx.x & 31, ty = threadIdx.x >> 5;
      __syncthreads();                  // reuse of tile across stride iterations
      #pragma unroll
      for (int r = 0; r < 32; r += 8)
        tile[ty + r][tx] = src[(size_t)(kx + ty + r) * 1024 + ny + tx];
      __syncthreads();
      #pragma unroll
      for (int r = 0; r < 32; r += 8)
        dst[(size_t)(ny + ty + r) * 1024 + kx + tx] = f2bf(tile[tx][ty + r]);
    } else if (b < 7232) {              // Wo^T (1024x64 -> 64x1024)
      int idx = b - 7168;
      int kx = (idx & 31) * 32, ny = (idx >> 5) * 32;
      int tx = threadIdx.x & 31, ty = threadIdx.x >> 5;
      __syncthreads();
      #pragma unroll
      for (int r = 0; r < 32; r += 8)
        tile[ty + r][tx] = Wo[(size_t)(kx + ty + r) * 64 + ny + tx];
      __syncthreads();
      #pragma unroll
      for (int r = 0; r < 32; r += 8)
        wot[(size_t)(ny + ty + r) * 1024 + kx + tx] = f2bf(tile[tx][ty + r]);
    } else {                            // seed out with bias (out is re-poisoned each call)
      int t = (b - 7232) * 256 + threadIdx.x;  // 65536 float4s
      float4 bi = *(const float4*)(bo + (t & 15) * 4);
      *(float4*)(out + (size_t)t * 4) = bi;
    }
  }
}

// ---------------- QKV projection GEMM v3.1 (149.4us config, minus sched_barrier pin) ----------------
// 128^2 tile, BK=32, 2-slot counted pipeline, 4 blocks/CU, grid 768.
// v4 depth-2 (3 blocks/CU): neutral. v5 no-LDS: FETCH 101MB -> HBM-bound, 96us
// (LDS staging is the traffic compressor, not just latency hiding).
// v3.1: sched_barrier(0) removed -- let the compiler hoist ds_reads (lgkm,
// barrier-legal) ahead of the stage gloads instead of pinning program order.

__global__ __launch_bounds__(256, 4) void qkv_gemm3(
    const unsigned short* __restrict__ Xb,
    const unsigned short* __restrict__ Wstk,
    unsigned short* __restrict__ Oq, unsigned short* __restrict__ Ok,
    unsigned short* __restrict__ Ovt) {
  constexpr int Kd = 1024, BK = 32, NT = Kd / BK;  // 32 k-tiles
  __shared__ __align__(16) unsigned short As[2][128 * 32];
  __shared__ __align__(16) unsigned short Bs[2][128 * 32];

  int wg = blockIdx.x;                       // 768 = 24 m-tiles x 32 n-tiles
  int swz8 = (wg & 7) * 96 + (wg >> 3);      // bijective XCD swizzle (cpx=96)
  int mt = swz8 >> 5, ntile = swz8 & 31;     // ntile fastest: same-XCD neighbors share A
  int m0 = mt * 128, n0 = ntile * 128;

  int tid = threadIdx.x, lane = tid & 63, wave = tid >> 6;
  int wm = wave >> 1, wn = wave & 1;         // 2x2 wave grid; per-wave C = 64x64
  int l15 = lane & 15, quad = lane >> 4;

  // staging: i = tid, tid+256 -> row = i>>2 (0..127), granule g = i&3.
  // global granule = g ^ ((row>>1)&3); LDS dest linear i*16B.
  int sr0 = tid >> 2, sg0 = tid & 3;
  int sr1 = (tid + 256) >> 2, sg1 = (tid + 256) & 3;
  int ga0 = (sg0 ^ ((sr0 >> 1) & 3)) * 8, ga1 = (sg1 ^ ((sr1 >> 1) & 3)) * 8;

  f32x4 acc[4][4] = {};

  // prologue: stage tile 0 into slot 0
  gload_lds16(Wstk + (size_t)(m0 + sr0) * Kd + ga0, &As[0][tid * 8]);
  gload_lds16(Wstk + (size_t)(m0 + sr1) * Kd + ga1, &As[0][(tid + 256) * 8]);
  gload_lds16(Xb + (size_t)(n0 + sr0) * Kd + ga0, &Bs[0][tid * 8]);
  gload_lds16(Xb + (size_t)(n0 + sr1) * Kd + ga1, &Bs[0][(tid + 256) * 8]);

  for (int i = 0; i < NT; ++i) {
    int cur = i & 1;
    asm volatile("s_waitcnt vmcnt(0)" ::: "memory");   // tile i landed (mine)
    __builtin_amdgcn_s_barrier();                      // all waves' tile i visible

    if (i + 1 < NT) {                                  // stage tile i+1 -> other slot
      int k0 = (i + 1) * BK;
      gload_lds16(Wstk + (size_t)(m0 + sr0) * Kd + k0 + ga0, &As[cur ^ 1][tid * 8]);
      gload_lds16(Wstk + (size_t)(m0 + sr1) * Kd + k0 + ga1, &As[cur ^ 1][(tid + 256) * 8]);
      gload_lds16(Xb + (size_t)(n0 + sr0) * Kd + k0 + ga0, &Bs[cur ^ 1][tid * 8]);
      gload_lds16(Xb + (size_t)(n0 + sr1) * Kd + k0 + ga1, &Bs[cur ^ 1][(tid + 256) * 8]);
    }

    // compute tile i from slot cur: 8 ds_read_b128 + 16 MFMA
    {
      const unsigned short* Ab = As[cur];
      const unsigned short* Bb = Bs[cur];
      short8 bfr[4];
      #pragma unroll
      for (int ni = 0; ni < 4; ++ni) {
        int row = wn * 64 + ni * 16 + l15;
        bfr[ni] = *(const short8*)&Bb[row * 32 + ((quad ^ ((row >> 1) & 3)) * 8)];
      }
      __builtin_amdgcn_s_setprio(1);
      #pragma unroll
      for (int mi = 0; mi < 4; ++mi) {
        int row = wm * 64 + mi * 16 + l15;
        short8 af = *(const short8*)&Ab[row * 32 + ((quad ^ ((row >> 1) & 3)) * 8)];
        #pragma unroll
        for (int ni = 0; ni < 4; ++ni)
          acc[mi][ni] = __builtin_amdgcn_mfma_f32_16x16x32_bf16(af, bfr[ni], acc[mi][ni], 0, 0, 0);
      }
      __builtin_amdgcn_s_setprio(0);
    }
  }

  // epilogue: region by m (mt 0-7 q, 8-15 k, 16-23 v); per-lane rows = 4 consecutive d
  int region = mt >> 3;
  if (region < 2) {
    unsigned short* O = (region == 0) ? Oq : Ok;
    float scale = (region == 0) ? 0.0450842200f : 1.0f;  // 1/sqrt(1024)*log2(e) for Q
    #pragma unroll
    for (int mi = 0; mi < 4; ++mi) {
      int dg = (m0 - region * 1024) + wm * 64 + mi * 16 + quad * 4;
      int h = dg >> 6, d0 = dg & 63;
      #pragma unroll
      for (int ni = 0; ni < 4; ++ni) {
        int t = n0 + wn * 64 + ni * 16 + l15;
        int b = t >> 11, tt = t & 2047;
        uint2 pk;
        pk.x = pk2bf(acc[mi][ni][0] * scale, acc[mi][ni][1] * scale);
        pk.y = pk2bf(acc[mi][ni][2] * scale, acc[mi][ni][3] * scale);
        *(uint2*)(O + (((size_t)(b * 16 + h) * 2048 + tt) << 6) + d0) = pk;
      }
    }
  } else {
    #pragma unroll
    for (int mi = 0; mi < 4; ++mi) {
      int dg = (m0 - 2048) + wm * 64 + mi * 16 + quad * 4;
      int h = dg >> 6, d0 = dg & 63;
      #pragma unroll
      for (int ni = 0; ni < 4; ++ni) {
        int t = n0 + wn * 64 + ni * 16 + l15;
        int b = t >> 11, tt = t & 2047;
        #pragma unroll
        for (int r = 0; r < 4; ++r)
          Ovt[(((size_t)(b * 16 + h) * 64 + d0 + r) << 11) + tt] = f2bf(acc[mi][ni][r]);
      }
    }
  }
}

// ---------------- fused causal flash attention v14.1: + hoisted Wo^T frags ----------------
// v14 (shuffle-light softmax) + the epilogue's 8 Wo^T B-frag loads hoisted above the
// main loop: loop-invariant, L2-hot, previously serialized the epilogue behind the
// loop tail. +32 VGPR (52 -> ~84), still well within the 4-blocks/CU budget.

__global__ __launch_bounds__(256, 4) void attn14(
    const unsigned short* __restrict__ Qg, const unsigned short* __restrict__ Kg,
    const unsigned short* __restrict__ Vtg, const unsigned short* __restrict__ Wot,
    float* __restrict__ out) {
  constexpr int T = 2048;
  __shared__ __align__(16) unsigned short Ks[2][64 * 64];   // [tok][d], XOR-swz
  __shared__ __align__(16) unsigned short Vs[2][64 * 64];   // [d][tok], XOR-swz
  __shared__ __align__(16) unsigned short Ps[4][16 * 64];   // per-wave, XOR-swz
  int bh = blockIdx.x;
  int by = blockIdx.y;
  int g = by >> 3, w8 = by & 7;
  int qt = (g == 0) ? w8 : (g == 1) ? (15 - w8) : (g == 2) ? (16 + w8) : (31 - w8);
  int tid = threadIdx.x, lane = tid & 63, wave = tid >> 6;
  int l15 = lane & 15, quad = lane >> 4;
  int swz = l15 & 7;
  const unsigned short* Qb = Qg + (size_t)bh * T * 64;
  const unsigned short* Kb = Kg + (size_t)bh * T * 64;
  const unsigned short* Vb = Vtg + (size_t)bh * 64 * T;
  int h = bh & 15, b = bh >> 4;
  int qw = qt * 64 + wave * 16;

  short8 qf[2];
  #pragma unroll
  for (int s = 0; s < 2; ++s)
    qf[s] = *(const short8*)(Qb + (size_t)(qw + l15) * 64 + quad * 8 + 32 * s);

  // hoisted Wo^T B-frags: col n=l15 (dout), k=dh h*64+quad*8+32s (loop-invariant)
  short8 wof[4][2];
  #pragma unroll
  for (int nt = 0; nt < 4; ++nt)
    #pragma unroll
    for (int s = 0; s < 2; ++s)
      wof[nt][s] = *(const short8*)(Wot + (size_t)(nt * 16 + l15) * 1024 + h * 64 + quad * 8 + 32 * s);

  f32x4 Oacc[4] = {};
  float m_run = -__builtin_inff();
  float l_part = 0.f;                      // per-lane partial denominator

  int srow = tid >> 3, sc8 = tid & 7;
  int sdst = srow * 64 + ((sc8 ^ (srow & 7)) * 8);

  ushort8v kpre[2], vpre[2];
  #pragma unroll
  for (int r = 0; r < 2; ++r) {
    kpre[r] = *(const ushort8v*)(Kb + (size_t)(srow + 32 * r) * 64 + sc8 * 8);
    vpre[r] = *(const ushort8v*)(Vb + (size_t)(srow + 32 * r) * T + sc8 * 8);
  }
  *(ushort8v*)&Ks[0][sdst] = kpre[0];
  *(ushort8v*)&Ks[0][sdst + 2048] = kpre[1];
  *(ushort8v*)&Vs[0][sdst] = vpre[0];
  *(ushort8v*)&Vs[0][sdst + 2048] = vpre[1];
  __syncthreads();

  for (int kt = 0; kt <= qt; ++kt) {
    const unsigned short* Kl = Ks[kt & 1];
    const unsigned short* Vl = Vs[kt & 1];
    unsigned short* Kn = Ks[(kt & 1) ^ 1];
    unsigned short* Vn = Vs[(kt & 1) ^ 1];

    if (kt < qt) {
      #pragma unroll
      for (int r = 0; r < 2; ++r) {
        kpre[r] = *(const ushort8v*)(Kb + (size_t)((kt + 1) * 64 + srow + 32 * r) * 64 + sc8 * 8);
        vpre[r] = *(const ushort8v*)(Vb + (size_t)(srow + 32 * r) * T + (kt + 1) * 64 + sc8 * 8);
      }
    }

    f32x4 S[4] = {};
    __builtin_amdgcn_s_setprio(1);
    #pragma unroll
    for (int s = 0; s < 2; ++s)
      #pragma unroll
      for (int mi = 0; mi < 4; ++mi) {
        short8 kf = *(const short8*)&Kl[(mi * 16 + l15) * 64 + ((quad + 4 * s) ^ swz) * 8];
        S[mi] = __builtin_amdgcn_mfma_f32_16x16x32_bf16(kf, qf[s], S[mi], 0, 0, 0);
      }
    __builtin_amdgcn_s_setprio(0);

    if (kt == qt) {  // diagonal tile: causal mask
      int ql = wave * 16 + l15;
      #pragma unroll
      for (int mi = 0; mi < 4; ++mi) {
        int tokl = mi * 16 + quad * 4;
        #pragma unroll
        for (int r = 0; r < 4; ++r)
          if (tokl + r > ql) S[mi][r] = -__builtin_inff();
      }
    }

    // per-lane max (no shuffles yet)
    float t0 = fmaxf(fmaxf(S[0][0], S[0][1]), fmaxf(S[0][2], S[0][3]));
    float t1 = fmaxf(fmaxf(S[1][0], S[1][1]), fmaxf(S[1][2], S[1][3]));
    float t2 = fmaxf(fmaxf(S[2][0], S[2][1]), fmaxf(S[2][2], S[2][3]));
    float t3 = fmaxf(fmaxf(S[3][0], S[3][1]), fmaxf(S[3][2], S[3][3]));
    float vloc = fmaxf(fmaxf(t0, t1), fmaxf(t2, t3));

    // defer-first: all-lanes check on LOCAL max == check on reduced max.
    float mnew = m_run;
    bool defer = __all(vloc - m_run <= 8.f) != 0;
    if (!defer) {
      float vmax = fmaxf(vloc, __shfl_xor(vloc, 16));
      vmax = fmaxf(vmax, __shfl_xor(vmax, 32));
      mnew = fmaxf(m_run, vmax);
      float alpha = __builtin_amdgcn_exp2f(m_run - mnew);
      m_run = mnew;
      l_part *= alpha;
      #pragma unroll
      for (int jd = 0; jd < 4; ++jd)
        #pragma unroll
        for (int r = 0; r < 4; ++r)
          Oacc[jd][r] *= alpha;
    }

    float rs = 0.f;
    #pragma unroll
    for (int mi = 0; mi < 4; ++mi) {
      float p0 = __builtin_amdgcn_exp2f(S[mi][0] - mnew);
      float p1 = __builtin_amdgcn_exp2f(S[mi][1] - mnew);
      float p2 = __builtin_amdgcn_exp2f(S[mi][2] - mnew);
      float p3 = __builtin_amdgcn_exp2f(S[mi][3] - mnew);
      rs += (p0 + p1) + (p2 + p3);
      uint2 pk;
      pk.x = pk2bf(p0, p1);
      pk.y = pk2bf(p2, p3);
      int gg = (2 * mi + (quad >> 1)) ^ swz;
      *(uint2*)&Ps[wave][l15 * 64 + gg * 8 + (quad & 1) * 4] = pk;
    }
    l_part += rs;                       // per-lane partial; reduced once at end

    if (kt < qt) {
      *(ushort8v*)&Kn[sdst] = kpre[0];
      *(ushort8v*)&Kn[sdst + 2048] = kpre[1];
      *(ushort8v*)&Vn[sdst] = vpre[0];
      *(ushort8v*)&Vn[sdst + 2048] = vpre[1];
    }

    __builtin_amdgcn_s_setprio(1);
    #pragma unroll
    for (int s = 0; s < 2; ++s) {
      short8 pf = *(const short8*)&Ps[wave][l15 * 64 + ((quad + 4 * s) ^ swz) * 8];
      #pragma unroll
      for (int jd = 0; jd < 4; ++jd) {
        short8 vfr = *(const short8*)&Vl[(jd * 16 + l15) * 64 + ((quad + 4 * s) ^ swz) * 8];
        Oacc[jd] = __builtin_amdgcn_mfma_f32_16x16x32_bf16(vfr, pf, Oacc[jd], 0, 0, 0);
      }
    }
    __builtin_amdgcn_s_setprio(0);
    if (kt < qt) __syncthreads();
  }

  // final denominator reduce (2 shuffles total)
  float l_run = l_part + __shfl_xor(l_part, 16);
  l_run += __shfl_xor(l_run, 32);

  // ---- fused out-projection epilogue (no barriers: each wave uses only its own Ps slot) ----
  {
    float linv = 1.f / l_run;
    unsigned short* Yl = &Ps[wave][0];
    #pragma unroll
    for (int jd = 0; jd < 4; ++jd) {
      uint2 pk;
      pk.x = pk2bf(Oacc[jd][0] * linv, Oacc[jd][1] * linv);
      pk.y = pk2bf(Oacc[jd][2] * linv, Oacc[jd][3] * linv);
      int gg = (jd * 2 + (quad >> 1)) ^ swz;
      *(uint2*)&Yl[l15 * 64 + gg * 8 + (quad & 1) * 4] = pk;
    }
    f32x4 acc2[4] = {};
    #pragma unroll
    for (int s = 0; s < 2; ++s) {
      short8 ya = *(const short8*)&Yl[l15 * 64 + (((quad + 4 * s) ^ swz) * 8)];
      #pragma unroll
      for (int nt = 0; nt < 4; ++nt)
        acc2[nt] = __builtin_amdgcn_mfma_f32_16x16x32_bf16(ya, wof[nt][s], acc2[nt], 0, 0, 0);
    }
    int q0 = b * 2048 + qt * 64 + wave * 16 + quad * 4;
    #pragma unroll
    for (int nt = 0; nt < 4; ++nt)
      #pragma unroll
      for (int r = 0; r < 4; ++r)
        atomicAdd(&out[(size_t)(q0 + r) * 64 + nt * 16 + l15], acc2[nt][r]);
  }
}

// ---------------- launcher (3 kernels total) ----------------

extern "C" void kernel_launch(void* const* d_in, const int* in_sizes, int n_in,
                              void* d_out, int out_size, void* d_ws, size_t ws_size,
                              hipStream_t stream) {
  const float* x  = (const float*)d_in[0];
  const float* Wq = (const float*)d_in[1];
  const float* Wk = (const float*)d_in[2];
  const float* Wv = (const float*)d_in[3];
  const float* Wo = (const float*)d_in[4];
  const float* bo = (const float*)d_in[5];
  float* out = (float*)d_out;
  char* ws = (char*)d_ws;

  unsigned short* xb  = (unsigned short*)(ws);                       // 8 MB  [4096][1024]
  unsigned short* wqt = (unsigned short*)(ws + (8ull << 20));        // 2 MB Wq^T (head of contiguous [3072][1024] W-stack)
  unsigned short* wkt = (unsigned short*)(ws + (10ull << 20));       // 2 MB Wk^T (stack middle)
  unsigned short* wvt = (unsigned short*)(ws + (12ull << 20));       // 2 MB Wv^T (stack tail)
  unsigned short* wot = (unsigned short*)(ws + (14ull << 20));       // 128 KB Wo^T
  unsigned short* q   = (unsigned short*)(ws + (15ull << 20));       // 8 MB  [b][h][t][d]
  unsigned short* k   = (unsigned short*)(ws + (23ull << 20));       // 8 MB  [b][h][t][d]
  unsigned short* vt  = (unsigned short*)(ws + (31ull << 20));       // 8 MB  [b][h][d][t]

  prep<<<1024, 256, 0, stream>>>(x, Wq, Wk, Wv, Wo, bo, xb, wqt, wkt, wvt, wot, out);
  qkv_gemm3<<<768, 256, 0, stream>>>(xb, wqt, q, k, vt);
  attn14<<<dim3(32, 32), 256, 0, stream>>>(q, k, vt, wot, out);
}